// Round 1
// baseline (583.617 us; speedup 1.0000x reference)
//
#include <hip/hip_runtime.h>
#include <math.h>

#define NROWS 8192
#define NDET  4096

// ---------------- workspace layout (float element offsets) ----------------
// idxT   [8][N]   int32   @ 0          (65536)
// sgnT   [8][N]   float   @ 65536      (65536)
// fw     folded pn weights@ 131072     (4096 reserved; 2720 used)
// h3buf  [320][N] float   @ 135168     (2621440)   (pointnet per-point outputs)
// h0T    [128][N] float   @ 2756608    (1048576)
// aggT   [128][N] float   @ 3805184    (1048576)   (reused for all 3 layers)
// h1T    [64][N]  float   @ 4853760    (524288)
// h2T    [64][N]  float   @ 5378048    (524288)
// total 5902336 floats = 23.6 MB

static constexpr int OFF_SGN = 65536;
static constexpr int OFF_FW  = 131072;
static constexpr int OFF_H3  = 135168;
static constexpr int OFF_H0  = 2756608;
static constexpr int OFF_AGG = 3805184;
static constexpr int OFF_H1  = 4853760;
static constexpr int OFF_H2  = 5378048;

// ---- fold BatchNorm into pointnet conv weights ----
// fw layout: fw1[3][16] @0, fb1[16] @48, fw2[16][32] @64, fb2[32] @576,
//            fw3[32][64] @608, fb3[64] @2656
__global__ void k_fold(const float* __restrict__ w1, const float* __restrict__ b1,
                       const float* __restrict__ g1, const float* __restrict__ be1,
                       const float* __restrict__ m1, const float* __restrict__ v1,
                       const float* __restrict__ w2, const float* __restrict__ b2,
                       const float* __restrict__ g2, const float* __restrict__ be2,
                       const float* __restrict__ m2, const float* __restrict__ v2,
                       const float* __restrict__ w3, const float* __restrict__ b3,
                       const float* __restrict__ g3, const float* __restrict__ be3,
                       const float* __restrict__ m3, const float* __restrict__ v3,
                       float* __restrict__ fw)
{
    int t = threadIdx.x;
    for (int i = t; i < 48; i += 256) { int d = i & 15; fw[i]       = w1[i] * g1[d] * rsqrtf(v1[d] + 1e-5f); }
    for (int i = t; i < 16; i += 256) {                 fw[48 + i]  = (b1[i] - m1[i]) * g1[i] * rsqrtf(v1[i] + 1e-5f) + be1[i]; }
    for (int i = t; i < 512; i += 256){ int d = i & 31; fw[64 + i]  = w2[i] * g2[d] * rsqrtf(v2[d] + 1e-5f); }
    for (int i = t; i < 32; i += 256) {                 fw[576 + i] = (b2[i] - m2[i]) * g2[i] * rsqrtf(v2[i] + 1e-5f) + be2[i]; }
    for (int i = t; i < 2048; i += 256){int d = i & 63; fw[608 + i] = w3[i] * g3[d] * rsqrtf(v3[d] + 1e-5f); }
    for (int i = t; i < 64; i += 256) {                 fw[2656 + i]= (b3[i] - m3[i]) * g3[i] * rsqrtf(v3[i] + 1e-5f) + be3[i]; }
}

// ---- sparse extraction: one block per row, scan the half that can hold neighbors ----
__global__ void k_extract(const float* __restrict__ nodeA, const float* __restrict__ edgeA,
                          int* __restrict__ idxT, float* __restrict__ sgnT)
{
    int row = blockIdx.x, t = threadIdx.x;
    const float* src; int col0, fill;
    if (row < NDET) { src = nodeA + (size_t)row * NROWS + NDET; col0 = NDET; fill = NDET; }
    else            { src = edgeA + (size_t)row * NROWS;        col0 = 0;    fill = 0;    }
    __shared__ int scnt;
    if (t == 0) scnt = 0;
    __syncthreads();
    const float4* s4 = (const float4*)src;
    #pragma unroll
    for (int it = 0; it < 4; ++it) {
        float4 v = s4[t + it * 256];
        int cb = col0 + (t + it * 256) * 4;
        if (v.x != 0.f) { int p = atomicAdd(&scnt, 1); idxT[p * NROWS + row] = cb;     sgnT[p * NROWS + row] = v.x; }
        if (v.y != 0.f) { int p = atomicAdd(&scnt, 1); idxT[p * NROWS + row] = cb + 1; sgnT[p * NROWS + row] = v.y; }
        if (v.z != 0.f) { int p = atomicAdd(&scnt, 1); idxT[p * NROWS + row] = cb + 2; sgnT[p * NROWS + row] = v.z; }
        if (v.w != 0.f) { int p = atomicAdd(&scnt, 1); idxT[p * NROWS + row] = cb + 3; sgnT[p * NROWS + row] = v.w; }
    }
    __syncthreads();
    for (int p = scnt + t; p < 8; p += 256) { idxT[p * NROWS + row] = fill; sgnT[p * NROWS + row] = 0.f; }
}

// ---- pointnet: thread = (row, point); writes h3buf[(p*64+f)][row] ----
__global__ void k_pointnet(const float* __restrict__ x, const float* __restrict__ fw,
                           float* __restrict__ h3buf)
{
    int lane = threadIdx.x & 63;
    int p    = threadIdx.x >> 6;           // 0..4 (block = 320 threads)
    int row  = blockIdx.x * 64 + lane;
    float a0 = x[row * 74 + 64 + p];
    float a1 = x[row * 74 + 69 + p];
    const float* fw1 = fw;        const float* fb1 = fw + 48;
    const float* fw2 = fw + 64;   const float* fb2 = fw + 576;
    const float* fw3 = fw + 608;  const float* fb3 = fw + 2656;
    float h1[16];
    #pragma unroll
    for (int d = 0; d < 16; ++d)
        h1[d] = fmaxf(0.f, a0 * fw1[d] + a1 * fw1[16 + d] + fb1[d]);
    float h2[32];
    #pragma unroll
    for (int e = 0; e < 32; ++e) {
        float s = fb2[e];
        #pragma unroll
        for (int d = 0; d < 16; ++d) s += h1[d] * fw2[d * 32 + e];
        h2[e] = fmaxf(0.f, s);
    }
    for (int f = 0; f < 64; ++f) {
        float s = fb3[f];
        #pragma unroll
        for (int e = 0; e < 32; ++e) s += h2[e] * fw3[e * 64 + f];
        h3buf[(p * 64 + f) * NROWS + row] = s;
    }
}

// ---- assemble h0T: first 64 channels = x[:, :64] transposed, last 64 = max over points ----
__global__ void k_assemble(const float* __restrict__ x, const float* __restrict__ h3buf,
                           float* __restrict__ h0T)
{
    int g = blockIdx.x * 256 + threadIdx.x;    // grid 4096 blocks -> 128*8192 threads
    int k = g >> 13, row = g & 8191;
    float v;
    if (k < 64) v = x[row * 74 + k];
    else {
        int f = k - 64;
        v = h3buf[f * NROWS + row];
        #pragma unroll
        for (int p = 1; p < 5; ++p) v = fmaxf(v, h3buf[(p * 64 + f) * NROWS + row]);
    }
    h0T[k * NROWS + row] = v;
}

// ---- sparse aggregation: aggT[k][row] = h[k][row] + sum_j sgn * h[k][nbr_j] ----
template<int F>
__global__ void k_gather(const float* __restrict__ hT, const int* __restrict__ idxT,
                         const float* __restrict__ sgnT, float* __restrict__ aggT)
{
    int g = blockIdx.x * 256 + threadIdx.x;    // grid F*8192/256
    int k = g >> 13, row = g & 8191;
    const float* hk = hT + (size_t)k * NROWS;
    float acc = hk[row];
    #pragma unroll
    for (int j = 0; j < 8; ++j) {
        int nb   = idxT[j * NROWS + row];
        float sg = sgnT[j * NROWS + row];
        acc += sg * hk[nb];
    }
    aggT[k * NROWS + row] = acc;
}

// ---- skinny GEMM: out[d][row] = act( cat(h,agg)[row] . W[:,d] + b[d] ) ----
// thread = (row, 4 channels); node/edge weight choice is block-uniform.
template<int F, bool RELU>
__global__ void k_gemm(const float* __restrict__ hT, const float* __restrict__ aggT,
                       const float* __restrict__ wn, const float* __restrict__ we,
                       const float* __restrict__ bn, const float* __restrict__ be,
                       float* __restrict__ outT)
{
    int row = blockIdx.x * 256 + threadIdx.x;  // grid.x = 32
    int d0  = blockIdx.y * 4;                  // grid.y = 16
    bool isnode = (blockIdx.x < 16);           // 256-row blocks: uniform
    const float* W = isnode ? wn : we;
    const float* B = isnode ? bn : be;
    float acc[4];
    #pragma unroll
    for (int dd = 0; dd < 4; ++dd) acc[dd] = B[d0 + dd];
    #pragma unroll
    for (int half = 0; half < 2; ++half) {
        const float* src = half ? aggT : hT;
        const float* Wh  = W + half * F * 64;
        for (int k0 = 0; k0 < F; k0 += 8) {
            float in[8];
            #pragma unroll
            for (int kk = 0; kk < 8; ++kk) in[kk] = src[(size_t)(k0 + kk) * NROWS + row];
            #pragma unroll
            for (int kk = 0; kk < 8; ++kk)
                #pragma unroll
                for (int dd = 0; dd < 4; ++dd)
                    acc[dd] += in[kk] * Wh[(k0 + kk) * 64 + d0 + dd];
        }
    }
    #pragma unroll
    for (int dd = 0; dd < 4; ++dd) {
        float v = acc[dd];
        if (RELU) v = fmaxf(v, 0.f);
        outT[(size_t)(d0 + dd) * NROWS + row] = v;
    }
}

// ---- final layer: 128 -> 1 + sigmoid ----
__global__ void k_gc3(const float* __restrict__ h2T, const float* __restrict__ aggT,
                      const float* __restrict__ wn, const float* __restrict__ we,
                      const float* __restrict__ bn, const float* __restrict__ be,
                      float* __restrict__ out)
{
    int row = blockIdx.x * 256 + threadIdx.x;  // grid 32 blocks
    bool isnode = row < NDET;                  // wave-uniform (4096 % 64 == 0)
    const float* w = isnode ? wn : we;
    float acc = isnode ? bn[0] : be[0];
    #pragma unroll 8
    for (int k = 0; k < 64; ++k) acc += h2T[(size_t)k * NROWS + row] * w[k];
    #pragma unroll 8
    for (int k = 0; k < 64; ++k) acc += aggT[(size_t)k * NROWS + row] * w[64 + k];
    out[row] = 1.f / (1.f + expf(-acc));
}

extern "C" void kernel_launch(void* const* d_in, const int* in_sizes, int n_in,
                              void* d_out, int out_size, void* d_ws, size_t ws_size,
                              hipStream_t stream)
{
    const float* x      = (const float*)d_in[0];
    const float* nodeA  = (const float*)d_in[1];
    const float* edgeA  = (const float*)d_in[2];
    // pointnet params: for i=1..3 -> base 3 + (i-1)*6 : w,b,g,be,m,v
    const float* pw1 = (const float*)d_in[3];  const float* pb1 = (const float*)d_in[4];
    const float* pg1 = (const float*)d_in[5];  const float* pe1 = (const float*)d_in[6];
    const float* pm1 = (const float*)d_in[7];  const float* pv1 = (const float*)d_in[8];
    const float* pw2 = (const float*)d_in[9];  const float* pb2 = (const float*)d_in[10];
    const float* pg2 = (const float*)d_in[11]; const float* pe2 = (const float*)d_in[12];
    const float* pm2 = (const float*)d_in[13]; const float* pv2 = (const float*)d_in[14];
    const float* pw3 = (const float*)d_in[15]; const float* pb3 = (const float*)d_in[16];
    const float* pg3 = (const float*)d_in[17]; const float* pe3 = (const float*)d_in[18];
    const float* pm3 = (const float*)d_in[19]; const float* pv3 = (const float*)d_in[20];
    const float* g1wn = (const float*)d_in[21]; const float* g1we = (const float*)d_in[22];
    const float* g1bn = (const float*)d_in[23]; const float* g1be = (const float*)d_in[24];
    const float* g2wn = (const float*)d_in[25]; const float* g2we = (const float*)d_in[26];
    const float* g2bn = (const float*)d_in[27]; const float* g2be = (const float*)d_in[28];
    const float* g3wn = (const float*)d_in[29]; const float* g3we = (const float*)d_in[30];
    const float* g3bn = (const float*)d_in[31]; const float* g3be = (const float*)d_in[32];

    float* ws   = (float*)d_ws;
    int*   idxT = (int*)ws;
    float* sgnT = ws + OFF_SGN;
    float* fw   = ws + OFF_FW;
    float* h3   = ws + OFF_H3;
    float* h0T  = ws + OFF_H0;
    float* aggT = ws + OFF_AGG;
    float* h1T  = ws + OFF_H1;
    float* h2T  = ws + OFF_H2;
    float* out  = (float*)d_out;

    k_fold<<<1, 256, 0, stream>>>(pw1, pb1, pg1, pe1, pm1, pv1,
                                  pw2, pb2, pg2, pe2, pm2, pv2,
                                  pw3, pb3, pg3, pe3, pm3, pv3, fw);
    k_extract<<<NROWS, 256, 0, stream>>>(nodeA, edgeA, idxT, sgnT);
    k_pointnet<<<128, 320, 0, stream>>>(x, fw, h3);
    k_assemble<<<4096, 256, 0, stream>>>(x, h3, h0T);

    k_gather<128><<<4096, 256, 0, stream>>>(h0T, idxT, sgnT, aggT);
    k_gemm<128, true><<<dim3(32, 16), 256, 0, stream>>>(h0T, aggT, g1wn, g1we, g1bn, g1be, h1T);

    k_gather<64><<<2048, 256, 0, stream>>>(h1T, idxT, sgnT, aggT);
    k_gemm<64, true><<<dim3(32, 16), 256, 0, stream>>>(h1T, aggT, g2wn, g2we, g2bn, g2be, h2T);

    k_gather<64><<<2048, 256, 0, stream>>>(h2T, idxT, sgnT, aggT);
    k_gc3<<<32, 256, 0, stream>>>(h2T, aggT, g3wn, g3we, g3bn, g3be, out);
}